// Round 1
// baseline (390.723 us; speedup 1.0000x reference)
//
#include <hip/hip_runtime.h>
#include <math.h>

// Problem constants (from reference)
constexpr int B_ = 8, Q_ = 900, C_ = 256, H_ = 8, L_ = 4, P_ = 4, D_ = 32;
constexpr int S_ = 13294;
constexpr int BQ = B_ * Q_;   // 7200
constexpr int BS = B_ * S_;   // 106352

// ---------------------------------------------------------------------------
// Generic tiled f32 GEMM: C[M,N] = A[M,K] @ W[K,N] + bias (+ optional extra
// 2-row tail for the concat([q, object_shape]) @ w_off1 case) (+ optional relu)
// 64x64 tile, BK=16, 256 threads, 4x4 micro-tile per thread.
// ---------------------------------------------------------------------------
template<bool RELU, bool EXTRA2>
__global__ __launch_bounds__(256)
void gemm_bias(const float* __restrict__ A, const float* __restrict__ W,
               const float* __restrict__ bias, const float* __restrict__ extra,
               float* __restrict__ Cout, int M, int K, int N)
{
    __shared__ float As[16][68];   // transposed A tile, padded
    __shared__ float Ws[16][64];
    const int tid  = threadIdx.x;
    const int row0 = blockIdx.y * 64, col0 = blockIdx.x * 64;
    const int tx = tid & 15, ty = tid >> 4;
    const int arow = tid >> 2, akq = tid & 3;   // A-tile load mapping
    const int wr = tid >> 4, wc4 = tid & 15;    // W-tile load mapping

    float acc[4][4] = {};

    for (int k0 = 0; k0 < K; k0 += 16) {
        float4 av = make_float4(0.f, 0.f, 0.f, 0.f);
        const int gr = row0 + arow;
        if (gr < M) av = *(const float4*)(A + (size_t)gr * K + (k0 + akq * 4));
        As[akq * 4 + 0][arow] = av.x;
        As[akq * 4 + 1][arow] = av.y;
        As[akq * 4 + 2][arow] = av.z;
        As[akq * 4 + 3][arow] = av.w;

        const float4 wv = *(const float4*)(W + (size_t)(k0 + wr) * N + (col0 + wc4 * 4));
        *(float4*)&Ws[wr][wc4 * 4] = wv;
        __syncthreads();

        #pragma unroll
        for (int kk = 0; kk < 16; ++kk) {
            const float4 a = *(const float4*)&As[kk][ty * 4];
            const float4 b = *(const float4*)&Ws[kk][tx * 4];
            acc[0][0] += a.x * b.x; acc[0][1] += a.x * b.y; acc[0][2] += a.x * b.z; acc[0][3] += a.x * b.w;
            acc[1][0] += a.y * b.x; acc[1][1] += a.y * b.y; acc[1][2] += a.y * b.z; acc[1][3] += a.y * b.w;
            acc[2][0] += a.z * b.x; acc[2][1] += a.z * b.y; acc[2][2] += a.z * b.z; acc[2][3] += a.z * b.w;
            acc[3][0] += a.w * b.x; acc[3][1] += a.w * b.y; acc[3][2] += a.w * b.z; acc[3][3] += a.w * b.w;
        }
        __syncthreads();
    }

    #pragma unroll
    for (int i = 0; i < 4; ++i) {
        const int gr = row0 + ty * 4 + i;
        if (gr >= M) continue;
        float e0 = 0.f, e1 = 0.f;
        if (EXTRA2) { e0 = extra[(size_t)gr * 2]; e1 = extra[(size_t)gr * 2 + 1]; }
        #pragma unroll
        for (int j = 0; j < 4; ++j) {
            const int gc = col0 + tx * 4 + j;
            float v = acc[i][j] + bias[gc];
            if (EXTRA2)
                v += e0 * W[(size_t)K * N + gc] + e1 * W[(size_t)(K + 1) * N + gc];
            if (RELU) v = fmaxf(v, 0.f);
            Cout[(size_t)gr * N + gc] = v;
        }
    }
}

// ---------------------------------------------------------------------------
// Per-(b,q): spec term, attn = softmax(ax*ay + spec) over L*P=16 per head,
// sampling locations locs = clip(ref + off*obj_shape, 0, 1).
// 128 threads: tid = h*16 + (l*4+p)
// ---------------------------------------------------------------------------
__global__ __launch_bounds__(128)
void attn_loc_kernel(const float* __restrict__ q, const float* __restrict__ ax,
                     const float* __restrict__ ay, const float* __restrict__ bx,
                     const float* __restrict__ by, const float* __restrict__ refp,
                     const float* __restrict__ objs, const float* __restrict__ off,
                     float* __restrict__ attn_out, float* __restrict__ locs_out)
{
    const int bq = blockIdx.x;
    const int tid = threadIdx.x;
    __shared__ float sq[256];
    __shared__ float spec[8];
    __shared__ float sm[128];

    sq[tid]       = q[(size_t)bq * 256 + tid];
    sq[tid + 128] = q[(size_t)bq * 256 + tid + 128];
    __syncthreads();

    const int h = tid >> 4, lp = tid & 15;
    if (lp == 0) {
        float sx = 0.f, sy = 0.f;
        #pragma unroll
        for (int d = 0; d < 32; ++d) {
            const float qa = sq[h * 32 + d];
            sx += qa * bx[h * 32 + d];
            sy += qa * by[h * 32 + d];
        }
        spec[h] = sx * sy;
    }
    __syncthreads();

    const float val = ax[(size_t)bq * 128 + tid] * ay[(size_t)bq * 128 + tid] + spec[h];
    sm[tid] = val;
    __syncthreads();

    float mx = -1e30f;
    #pragma unroll
    for (int i = 0; i < 16; ++i) mx = fmaxf(mx, sm[h * 16 + i]);
    float sum = 0.f;
    #pragma unroll
    for (int i = 0; i < 16; ++i) sum += __expf(sm[h * 16 + i] - mx);
    attn_out[(size_t)bq * 128 + tid] = __expf(val - mx) / sum;

    // locations
    const int l = lp >> 2;
    const float os0 = objs[(size_t)bq * 2], os1 = objs[(size_t)bq * 2 + 1];
    const float r0 = refp[((size_t)bq * 4 + l) * 2];
    const float r1 = refp[((size_t)bq * 4 + l) * 2 + 1];
    const float o0 = off[(size_t)bq * 256 + tid * 2]     * os0;
    const float o1 = off[(size_t)bq * 256 + tid * 2 + 1] * os1;
    locs_out[(size_t)bq * 256 + tid * 2]     = fminf(fmaxf(r0 + o0, 0.f), 1.f);
    locs_out[(size_t)bq * 256 + tid * 2 + 1] = fminf(fmaxf(r1 + o1, 0.f), 1.f);
}

// ---------------------------------------------------------------------------
// Bilinear sampling + attention-weighted aggregation.
// One block per (b,q), 256 threads: tid = h*32 + d.
// ---------------------------------------------------------------------------
__device__ __forceinline__
float corner_val(const float* __restrict__ vb, int st, int Hl, int Wl,
                 int xi, int yi, float w, int hd)
{
    const bool valid = (xi >= 0) & (xi < Wl) & (yi >= 0) & (yi < Hl);
    const int idx = min(max(yi, 0), Hl - 1) * Wl + min(max(xi, 0), Wl - 1);
    const float g = vb[(size_t)(st + idx) * 256 + hd];
    return valid ? g * w : 0.f;
}

__global__ __launch_bounds__(256)
void sample_agg_kernel(const float* __restrict__ v, const float* __restrict__ locs,
                       const float* __restrict__ attn, float* __restrict__ agg)
{
    const int bq = blockIdx.x;
    const int b  = bq / Q_;
    const int tid = threadIdx.x;
    const int h = tid >> 5, d = tid & 31;
    const int hd = h * 32 + d;

    __shared__ float sl[256];
    __shared__ float sa[128];
    sl[tid] = locs[(size_t)bq * 256 + tid];
    if (tid < 128) sa[tid] = attn[(size_t)bq * 128 + tid];
    __syncthreads();

    const float* vb = v + (size_t)b * S_ * 256;

    const int Hl_arr[4] = {100, 50, 25, 13};
    const int Wl_arr[4] = {100, 50, 25, 13};
    const int st_arr[4] = {0, 10000, 12500, 13125};

    float acc = 0.f;
    #pragma unroll
    for (int lvl = 0; lvl < 4; ++lvl) {
        const int Hl = Hl_arr[lvl], Wl = Wl_arr[lvl], st = st_arr[lvl];
        #pragma unroll
        for (int p = 0; p < 4; ++p) {
            const int li = (h * 4 + lvl) * 4 + p;  // (h, lvl, p)
            const float lx = sl[li * 2], ly = sl[li * 2 + 1];
            const float a  = sa[li];
            const float x = lx * (float)Wl - 0.5f;
            const float y = ly * (float)Hl - 0.5f;
            const float x0f = floorf(x), y0f = floorf(y);
            const float fx = x - x0f, fy = y - y0f;
            const int x0 = (int)x0f, y0 = (int)y0f;
            const float w00 = (1.f - fx) * (1.f - fy);
            const float w10 = fx * (1.f - fy);
            const float w01 = (1.f - fx) * fy;
            const float w11 = fx * fy;
            float s = 0.f;
            s += corner_val(vb, st, Hl, Wl, x0,     y0,     w00, hd);
            s += corner_val(vb, st, Hl, Wl, x0 + 1, y0,     w10, hd);
            s += corner_val(vb, st, Hl, Wl, x0,     y0 + 1, w01, hd);
            s += corner_val(vb, st, Hl, Wl, x0 + 1, y0 + 1, w11, hd);
            acc += a * s;
        }
    }
    agg[(size_t)bq * 256 + tid] = acc;
}

// ---------------------------------------------------------------------------
extern "C" void kernel_launch(void* const* d_in, const int* in_sizes, int n_in,
                              void* d_out, int out_size, void* d_ws, size_t ws_size,
                              hipStream_t stream)
{
    const float* query   = (const float*)d_in[0];
    const float* refp    = (const float*)d_in[1];
    const float* x_in    = (const float*)d_in[2];
    const float* objs    = (const float*)d_in[3];
    // d_in[4], d_in[5]: spatial shapes / level starts — compile-time constants
    const float* w_q   = (const float*)d_in[6];
    const float* b_q   = (const float*)d_in[7];
    const float* w_v   = (const float*)d_in[8];
    const float* b_v   = (const float*)d_in[9];
    const float* w_o   = (const float*)d_in[10];
    const float* b_o   = (const float*)d_in[11];
    const float* w_off1 = (const float*)d_in[12];
    const float* b_off1 = (const float*)d_in[13];
    const float* w_off2 = (const float*)d_in[14];
    const float* b_off2 = (const float*)d_in[15];
    const float* w_ax  = (const float*)d_in[16];
    const float* b_ax  = (const float*)d_in[17];
    const float* w_ay  = (const float*)d_in[18];
    const float* b_ay  = (const float*)d_in[19];
    const float* bx    = (const float*)d_in[20];
    const float* by    = (const float*)d_in[21];

    float* ws = (float*)d_ws;
    float* v_ws    = ws;                            // BS*256
    float* q_ws    = v_ws    + (size_t)BS * 256;    // BQ*256
    float* hid_ws  = q_ws    + (size_t)BQ * 256;    // BQ*256
    float* off_ws  = hid_ws  + (size_t)BQ * 256;    // BQ*256
    float* ax_ws   = off_ws  + (size_t)BQ * 256;    // BQ*128
    float* ay_ws   = ax_ws   + (size_t)BQ * 128;    // BQ*128
    float* attn_ws = ay_ws   + (size_t)BQ * 128;    // BQ*128
    float* locs_ws = attn_ws + (size_t)BQ * 128;    // BQ*256
    float* agg_ws  = locs_ws + (size_t)BQ * 256;    // BQ*256

    const dim3 blk(256);

    // v = input_flatten @ w_v + b_v   (the big one: 106352 x 256 x 256)
    gemm_bias<false, false><<<dim3(256 / 64, (BS + 63) / 64), blk, 0, stream>>>(
        x_in, w_v, b_v, nullptr, v_ws, BS, 256, 256);

    // q = query @ w_q + b_q
    gemm_bias<false, false><<<dim3(256 / 64, (BQ + 63) / 64), blk, 0, stream>>>(
        query, w_q, b_q, nullptr, q_ws, BQ, 256, 256);

    // hid = relu(concat([q, obj_shape]) @ w_off1 + b_off1)
    gemm_bias<true, true><<<dim3(256 / 64, (BQ + 63) / 64), blk, 0, stream>>>(
        q_ws, w_off1, b_off1, objs, hid_ws, BQ, 256, 256);

    // offsets = hid @ w_off2 + b_off2
    gemm_bias<false, false><<<dim3(256 / 64, (BQ + 63) / 64), blk, 0, stream>>>(
        hid_ws, w_off2, b_off2, nullptr, off_ws, BQ, 256, 256);

    // attn_x / attn_y
    gemm_bias<false, false><<<dim3(128 / 64, (BQ + 63) / 64), blk, 0, stream>>>(
        q_ws, w_ax, b_ax, nullptr, ax_ws, BQ, 256, 128);
    gemm_bias<false, false><<<dim3(128 / 64, (BQ + 63) / 64), blk, 0, stream>>>(
        q_ws, w_ay, b_ay, nullptr, ay_ws, BQ, 256, 128);

    // attn softmax + sampling locations
    attn_loc_kernel<<<BQ, 128, 0, stream>>>(q_ws, ax_ws, ay_ws, bx, by, refp,
                                            objs, off_ws, attn_ws, locs_ws);

    // bilinear sample + weighted aggregate
    sample_agg_kernel<<<BQ, 256, 0, stream>>>(v_ws, locs_ws, attn_ws, agg_ws);

    // out = agg @ w_o + b_o
    gemm_bias<false, false><<<dim3(256 / 64, (BQ + 63) / 64), blk, 0, stream>>>(
        agg_ws, w_o, b_o, nullptr, (float*)d_out, BQ, 256, 256);
}

// Round 2
// 273.952 us; speedup vs baseline: 1.4262x; 1.4262x over previous
//
#include <hip/hip_runtime.h>
#include <hip/hip_bf16.h>
#include <math.h>

// Problem constants (from reference)
constexpr int B_ = 8, Q_ = 900, C_ = 256, H_ = 8, L_ = 4, P_ = 4, D_ = 32;
constexpr int S_ = 13294;
constexpr int BQ = B_ * Q_;   // 7200
constexpr int BS = B_ * S_;   // 106352

typedef __bf16 bf16x8 __attribute__((ext_vector_type(8)));
typedef float  f32x4  __attribute__((ext_vector_type(4)));

__device__ __forceinline__ void load_lds16(const void* g, void* lds) {
    __builtin_amdgcn_global_load_lds(
        (const __attribute__((address_space(1))) void*)g,
        (__attribute__((address_space(3))) void*)lds, 16, 0, 0);
}

// ---------------------------------------------------------------------------
// Transpose + cast: wt[n][k] = bf16(w[k][n]).  K,N multiples of 32.
// ---------------------------------------------------------------------------
__global__ __launch_bounds__(256)
void transpose_cast(const float* __restrict__ w, __bf16* __restrict__ wt,
                    int K, int N)
{
    __shared__ float tile[32][33];
    const int k0 = blockIdx.x * 32, n0 = blockIdx.y * 32;
    const int tx = threadIdx.x & 31, ty = threadIdx.x >> 5;  // ty 0..7
    #pragma unroll
    for (int i = 0; i < 4; ++i)
        tile[ty + 8 * i][tx] = w[(size_t)(k0 + ty + 8 * i) * N + n0 + tx];
    __syncthreads();
    #pragma unroll
    for (int i = 0; i < 4; ++i)
        wt[(size_t)(n0 + ty + 8 * i) * K + k0 + tx] = (__bf16)tile[tx][ty + 8 * i];
}

// ---------------------------------------------------------------------------
// bf16 MFMA GEMM: C[M,N] = A[M,K](f32) @ Wt[N,K](bf16, pre-transposed) + bias
// BM=BN=128, BK=32, 256 threads = 4 waves (2x2), 64x64 per wave,
// mfma_f32_16x16x32_bf16, 4x4 frags per wave.
// A: reg-staged (f32 -> bf16 cvt -> swizzled ds_write_b128)
// B: global_load_lds w/ source-side XOR swizzle (linear LDS dest).
// Swizzle: slot (outer, kcp) holds data kc = kcp ^ ((outer>>1)&3); 16B chunks.
// ---------------------------------------------------------------------------
template<bool HASBIAS>
__global__ __launch_bounds__(256)
void gemm_bf16(const float* __restrict__ A, const __bf16* __restrict__ Wt,
               const float* __restrict__ bias, float* __restrict__ Cout,
               int M, int K, int N)
{
    __shared__ __bf16 Asb[128 * 32];
    __shared__ __bf16 Bsb[128 * 32];
    char* const Asb_b = (char*)Asb;
    char* const Bsb_b = (char*)Bsb;

    const int tid  = threadIdx.x;
    const int wave = tid >> 6, lane = tid & 63;
    const int wr = wave >> 1, wc = wave & 1;       // 2x2 wave grid
    const int row0 = blockIdx.y * 128, col0 = blockIdx.x * 128;

    // A staging mapping: thread t -> row=t>>1, k-half=t&1 (16 floats each)
    const int st_row = tid >> 1, st_kh = tid & 1;

    // Precompute fragment LDS byte offsets (fixed across K-steps)
    int a_off[4], b_off[4];
    #pragma unroll
    for (int mi = 0; mi < 4; ++mi) {
        const int r   = wr * 64 + mi * 16 + (lane & 15);
        const int kcp = (lane >> 4) ^ ((r >> 1) & 3);
        a_off[mi] = r * 64 + kcp * 16;
    }
    #pragma unroll
    for (int ni = 0; ni < 4; ++ni) {
        const int c   = wc * 64 + ni * 16 + (lane & 15);
        const int kcp = (lane >> 4) ^ ((c >> 1) & 3);
        b_off[ni] = c * 64 + kcp * 16;
    }

    // B staging: per (wave, instr i): chunk c = (wave*2+i)*64 + lane
    int bst_col[2], bst_kc[2];
    #pragma unroll
    for (int i = 0; i < 2; ++i) {
        const int c   = (wave * 2 + i) * 64 + lane;
        const int col = c >> 2, kcp = c & 3;
        bst_col[i] = col;
        bst_kc[i]  = kcp ^ ((col >> 1) & 3);
    }

    f32x4 acc[4][4] = {};

    const int nk = K >> 5;
    for (int kt = 0; kt < nk; ++kt) {
        const int k0 = kt * 32;

        // ---- B tile: async global -> LDS (issue first, overlaps A staging)
        #pragma unroll
        for (int i = 0; i < 2; ++i) {
            const __bf16* g = Wt + (size_t)(col0 + bst_col[i]) * K + k0 + bst_kc[i] * 8;
            load_lds16(g, Bsb_b + (wave * 2 + i) * 1024);
        }

        // ---- A tile: f32 global -> bf16 regs -> swizzled LDS
        {
            const int gr = min(row0 + st_row, M - 1);
            const float* ga = A + (size_t)gr * K + k0 + st_kh * 16;
            const float4 f0 = ((const float4*)ga)[0];
            const float4 f1 = ((const float4*)ga)[1];
            const float4 f2 = ((const float4*)ga)[2];
            const float4 f3 = ((const float4*)ga)[3];
            bf16x8 c0, c1;
            c0[0] = (__bf16)f0.x; c0[1] = (__bf16)f0.y; c0[2] = (__bf16)f0.z; c0[3] = (__bf16)f0.w;
            c0[4] = (__bf16)f1.x; c0[5] = (__bf16)f1.y; c0[6] = (__bf16)f1.z; c0[7] = (__bf16)f1.w;
            c1[0] = (__bf16)f2.x; c1[1] = (__bf16)f2.y; c1[2] = (__bf16)f2.z; c1[3] = (__bf16)f2.w;
            c1[4] = (__bf16)f3.x; c1[5] = (__bf16)f3.y; c1[6] = (__bf16)f3.z; c1[7] = (__bf16)f3.w;
            const int sw  = (st_row >> 1) & 3;
            const int kc0 = (st_kh * 2)     ^ sw;
            const int kc1 = (st_kh * 2 + 1) ^ sw;
            *(bf16x8*)(Asb_b + st_row * 64 + kc0 * 16) = c0;
            *(bf16x8*)(Asb_b + st_row * 64 + kc1 * 16) = c1;
        }

        __syncthreads();   // drains vmcnt (global_load_lds) + lgkmcnt

        bf16x8 a[4], b[4];
        #pragma unroll
        for (int mi = 0; mi < 4; ++mi) a[mi] = *(const bf16x8*)(Asb_b + a_off[mi]);
        #pragma unroll
        for (int ni = 0; ni < 4; ++ni) b[ni] = *(const bf16x8*)(Bsb_b + b_off[ni]);

        #pragma unroll
        for (int mi = 0; mi < 4; ++mi)
            #pragma unroll
            for (int ni = 0; ni < 4; ++ni)
                acc[mi][ni] = __builtin_amdgcn_mfma_f32_16x16x32_bf16(
                    a[mi], b[ni], acc[mi][ni], 0, 0, 0);

        __syncthreads();
    }

    // Epilogue: C/D layout col=lane&15, row=(lane>>4)*4+reg
    #pragma unroll
    for (int ni = 0; ni < 4; ++ni) {
        const int colb = col0 + wc * 64 + ni * 16 + (lane & 15);
        const float bb = HASBIAS ? bias[colb] : 0.f;
        #pragma unroll
        for (int mi = 0; mi < 4; ++mi) {
            #pragma unroll
            for (int rr = 0; rr < 4; ++rr) {
                const int row = row0 + wr * 64 + mi * 16 + (lane >> 4) * 4 + rr;
                if (row < M) Cout[(size_t)row * N + colb] = acc[mi][ni][rr] + bb;
            }
        }
    }
}

// ---------------------------------------------------------------------------
// f32 tiled GEMM (kept for the q -> off1 -> off2 precision-critical chain)
// ---------------------------------------------------------------------------
template<bool RELU, bool EXTRA2>
__global__ __launch_bounds__(256)
void gemm_bias(const float* __restrict__ A, const float* __restrict__ W,
               const float* __restrict__ bias, const float* __restrict__ extra,
               float* __restrict__ Cout, int M, int K, int N)
{
    __shared__ float As[16][68];
    __shared__ float Ws[16][64];
    const int tid  = threadIdx.x;
    const int row0 = blockIdx.y * 64, col0 = blockIdx.x * 64;
    const int tx = tid & 15, ty = tid >> 4;
    const int arow = tid >> 2, akq = tid & 3;
    const int wr = tid >> 4, wc4 = tid & 15;

    float acc[4][4] = {};

    for (int k0 = 0; k0 < K; k0 += 16) {
        float4 av = make_float4(0.f, 0.f, 0.f, 0.f);
        const int gr = row0 + arow;
        if (gr < M) av = *(const float4*)(A + (size_t)gr * K + (k0 + akq * 4));
        As[akq * 4 + 0][arow] = av.x;
        As[akq * 4 + 1][arow] = av.y;
        As[akq * 4 + 2][arow] = av.z;
        As[akq * 4 + 3][arow] = av.w;

        const float4 wv = *(const float4*)(W + (size_t)(k0 + wr) * N + (col0 + wc4 * 4));
        *(float4*)&Ws[wr][wc4 * 4] = wv;
        __syncthreads();

        #pragma unroll
        for (int kk = 0; kk < 16; ++kk) {
            const float4 a = *(const float4*)&As[kk][ty * 4];
            const float4 b = *(const float4*)&Ws[kk][tx * 4];
            acc[0][0] += a.x * b.x; acc[0][1] += a.x * b.y; acc[0][2] += a.x * b.z; acc[0][3] += a.x * b.w;
            acc[1][0] += a.y * b.x; acc[1][1] += a.y * b.y; acc[1][2] += a.y * b.z; acc[1][3] += a.y * b.w;
            acc[2][0] += a.z * b.x; acc[2][1] += a.z * b.y; acc[2][2] += a.z * b.z; acc[2][3] += a.z * b.w;
            acc[3][0] += a.w * b.x; acc[3][1] += a.w * b.y; acc[3][2] += a.w * b.z; acc[3][3] += a.w * b.w;
        }
        __syncthreads();
    }

    #pragma unroll
    for (int i = 0; i < 4; ++i) {
        const int gr = row0 + ty * 4 + i;
        if (gr >= M) continue;
        float e0 = 0.f, e1 = 0.f;
        if (EXTRA2) { e0 = extra[(size_t)gr * 2]; e1 = extra[(size_t)gr * 2 + 1]; }
        #pragma unroll
        for (int j = 0; j < 4; ++j) {
            const int gc = col0 + tx * 4 + j;
            float v = acc[i][j] + bias[gc];
            if (EXTRA2)
                v += e0 * W[(size_t)K * N + gc] + e1 * W[(size_t)(K + 1) * N + gc];
            if (RELU) v = fmaxf(v, 0.f);
            Cout[(size_t)gr * N + gc] = v;
        }
    }
}

// ---------------------------------------------------------------------------
// Per-(b,q): spec term, softmax over L*P=16 per head, sampling locations.
// ---------------------------------------------------------------------------
__global__ __launch_bounds__(128)
void attn_loc_kernel(const float* __restrict__ q, const float* __restrict__ ax,
                     const float* __restrict__ ay, const float* __restrict__ bx,
                     const float* __restrict__ by, const float* __restrict__ refp,
                     const float* __restrict__ objs, const float* __restrict__ off,
                     float* __restrict__ attn_out, float* __restrict__ locs_out)
{
    const int bq = blockIdx.x;
    const int tid = threadIdx.x;
    __shared__ float sq[256];
    __shared__ float spec[8];
    __shared__ float sm[128];

    sq[tid]       = q[(size_t)bq * 256 + tid];
    sq[tid + 128] = q[(size_t)bq * 256 + tid + 128];
    __syncthreads();

    const int h = tid >> 4, lp = tid & 15;
    if (lp == 0) {
        float sx = 0.f, sy = 0.f;
        #pragma unroll
        for (int d = 0; d < 32; ++d) {
            const float qa = sq[h * 32 + d];
            sx += qa * bx[h * 32 + d];
            sy += qa * by[h * 32 + d];
        }
        spec[h] = sx * sy;
    }
    __syncthreads();

    const float val = ax[(size_t)bq * 128 + tid] * ay[(size_t)bq * 128 + tid] + spec[h];
    sm[tid] = val;
    __syncthreads();

    float mx = -1e30f;
    #pragma unroll
    for (int i = 0; i < 16; ++i) mx = fmaxf(mx, sm[h * 16 + i]);
    float sum = 0.f;
    #pragma unroll
    for (int i = 0; i < 16; ++i) sum += __expf(sm[h * 16 + i] - mx);
    attn_out[(size_t)bq * 128 + tid] = __expf(val - mx) / sum;

    const int l = lp >> 2;
    const float os0 = objs[(size_t)bq * 2], os1 = objs[(size_t)bq * 2 + 1];
    const float r0 = refp[((size_t)bq * 4 + l) * 2];
    const float r1 = refp[((size_t)bq * 4 + l) * 2 + 1];
    const float o0 = off[(size_t)bq * 256 + tid * 2]     * os0;
    const float o1 = off[(size_t)bq * 256 + tid * 2 + 1] * os1;
    locs_out[(size_t)bq * 256 + tid * 2]     = fminf(fmaxf(r0 + o0, 0.f), 1.f);
    locs_out[(size_t)bq * 256 + tid * 2 + 1] = fminf(fmaxf(r1 + o1, 0.f), 1.f);
}

// ---------------------------------------------------------------------------
// Bilinear sampling + attention-weighted aggregation.
// ---------------------------------------------------------------------------
__device__ __forceinline__
float corner_val(const float* __restrict__ vb, int st, int Hl, int Wl,
                 int xi, int yi, float w, int hd)
{
    const bool valid = (xi >= 0) & (xi < Wl) & (yi >= 0) & (yi < Hl);
    const int idx = min(max(yi, 0), Hl - 1) * Wl + min(max(xi, 0), Wl - 1);
    const float g = vb[(size_t)(st + idx) * 256 + hd];
    return valid ? g * w : 0.f;
}

__global__ __launch_bounds__(256)
void sample_agg_kernel(const float* __restrict__ v, const float* __restrict__ locs,
                       const float* __restrict__ attn, float* __restrict__ agg)
{
    const int bq = blockIdx.x;
    const int b  = bq / Q_;
    const int tid = threadIdx.x;
    const int h = tid >> 5, d = tid & 31;
    const int hd = h * 32 + d;

    __shared__ float sl[256];
    __shared__ float sa[128];
    sl[tid] = locs[(size_t)bq * 256 + tid];
    if (tid < 128) sa[tid] = attn[(size_t)bq * 128 + tid];
    __syncthreads();

    const float* vb = v + (size_t)b * S_ * 256;

    const int Hl_arr[4] = {100, 50, 25, 13};
    const int Wl_arr[4] = {100, 50, 25, 13};
    const int st_arr[4] = {0, 10000, 12500, 13125};

    float acc = 0.f;
    #pragma unroll
    for (int lvl = 0; lvl < 4; ++lvl) {
        const int Hl = Hl_arr[lvl], Wl = Wl_arr[lvl], st = st_arr[lvl];
        #pragma unroll
        for (int p = 0; p < 4; ++p) {
            const int li = (h * 4 + lvl) * 4 + p;
            const float lx = sl[li * 2], ly = sl[li * 2 + 1];
            const float a  = sa[li];
            const float x = lx * (float)Wl - 0.5f;
            const float y = ly * (float)Hl - 0.5f;
            const float x0f = floorf(x), y0f = floorf(y);
            const float fx = x - x0f, fy = y - y0f;
            const int x0 = (int)x0f, y0 = (int)y0f;
            const float w00 = (1.f - fx) * (1.f - fy);
            const float w10 = fx * (1.f - fy);
            const float w01 = (1.f - fx) * fy;
            const float w11 = fx * fy;
            float s = 0.f;
            s += corner_val(vb, st, Hl, Wl, x0,     y0,     w00, hd);
            s += corner_val(vb, st, Hl, Wl, x0 + 1, y0,     w10, hd);
            s += corner_val(vb, st, Hl, Wl, x0,     y0 + 1, w01, hd);
            s += corner_val(vb, st, Hl, Wl, x0 + 1, y0 + 1, w11, hd);
            acc += a * s;
        }
    }
    agg[(size_t)bq * 256 + tid] = acc;
}

// ---------------------------------------------------------------------------
extern "C" void kernel_launch(void* const* d_in, const int* in_sizes, int n_in,
                              void* d_out, int out_size, void* d_ws, size_t ws_size,
                              hipStream_t stream)
{
    const float* query   = (const float*)d_in[0];
    const float* refp    = (const float*)d_in[1];
    const float* x_in    = (const float*)d_in[2];
    const float* objs    = (const float*)d_in[3];
    const float* w_q   = (const float*)d_in[6];
    const float* b_q   = (const float*)d_in[7];
    const float* w_v   = (const float*)d_in[8];
    const float* b_v   = (const float*)d_in[9];
    const float* w_o   = (const float*)d_in[10];
    const float* b_o   = (const float*)d_in[11];
    const float* w_off1 = (const float*)d_in[12];
    const float* b_off1 = (const float*)d_in[13];
    const float* w_off2 = (const float*)d_in[14];
    const float* b_off2 = (const float*)d_in[15];
    const float* w_ax  = (const float*)d_in[16];
    const float* b_ax  = (const float*)d_in[17];
    const float* w_ay  = (const float*)d_in[18];
    const float* b_ay  = (const float*)d_in[19];
    const float* bx    = (const float*)d_in[20];
    const float* by    = (const float*)d_in[21];

    float* ws = (float*)d_ws;
    float* v_ws    = ws;                            // BS*256
    float* q_ws    = v_ws    + (size_t)BS * 256;    // BQ*256
    float* hid_ws  = q_ws    + (size_t)BQ * 256;    // BQ*256
    float* off_ws  = hid_ws  + (size_t)BQ * 256;    // BQ*256
    float* ax_ws   = off_ws  + (size_t)BQ * 256;    // BQ*128
    float* ay_ws   = ax_ws   + (size_t)BQ * 128;    // BQ*128
    float* attn_ws = ay_ws   + (size_t)BQ * 128;    // BQ*128
    float* locs_ws = attn_ws + (size_t)BQ * 128;    // BQ*256
    float* agg_ws  = locs_ws + (size_t)BQ * 256;    // BQ*256
    __bf16* wt_v  = (__bf16*)(agg_ws + (size_t)BQ * 256);  // 256*256
    __bf16* wt_o  = wt_v  + 256 * 256;                     // 256*256
    __bf16* wt_ax = wt_o  + 256 * 256;                     // 128*256
    __bf16* wt_ay = wt_ax + 128 * 256;                     // 128*256

    const dim3 blk(256);

    // Pre-pass: transpose+cast the bf16-path weights (tiny)
    transpose_cast<<<dim3(8, 8), blk, 0, stream>>>(w_v,  wt_v,  256, 256);
    transpose_cast<<<dim3(8, 8), blk, 0, stream>>>(w_o,  wt_o,  256, 256);
    transpose_cast<<<dim3(8, 4), blk, 0, stream>>>(w_ax, wt_ax, 256, 128);
    transpose_cast<<<dim3(8, 4), blk, 0, stream>>>(w_ay, wt_ay, 256, 128);

    // v = input_flatten @ w_v + b_v  (bf16 MFMA)
    gemm_bf16<true><<<dim3(2, (BS + 127) / 128), blk, 0, stream>>>(
        x_in, wt_v, b_v, v_ws, BS, 256, 256);

    // q = query @ w_q + b_q  (f32 — feeds the location-critical chain)
    gemm_bias<false, false><<<dim3(4, (BQ + 63) / 64), blk, 0, stream>>>(
        query, w_q, b_q, nullptr, q_ws, BQ, 256, 256);

    // hid = relu(concat([q, obj]) @ w_off1 + b_off1)  (f32)
    gemm_bias<true, true><<<dim3(4, (BQ + 63) / 64), blk, 0, stream>>>(
        q_ws, w_off1, b_off1, objs, hid_ws, BQ, 256, 256);

    // offsets = hid @ w_off2 + b_off2  (f32)
    gemm_bias<false, false><<<dim3(4, (BQ + 63) / 64), blk, 0, stream>>>(
        hid_ws, w_off2, b_off2, nullptr, off_ws, BQ, 256, 256);

    // attn_x / attn_y  (bf16 MFMA — softmax path, error-tolerant)
    gemm_bf16<true><<<dim3(1, (BQ + 127) / 128), blk, 0, stream>>>(
        q_ws, wt_ax, b_ax, ax_ws, BQ, 256, 128);
    gemm_bf16<true><<<dim3(1, (BQ + 127) / 128), blk, 0, stream>>>(
        q_ws, wt_ay, b_ay, ay_ws, BQ, 256, 128);

    // attn softmax + sampling locations
    attn_loc_kernel<<<BQ, 128, 0, stream>>>(q_ws, ax_ws, ay_ws, bx, by, refp,
                                            objs, off_ws, attn_ws, locs_ws);

    // bilinear sample + weighted aggregate
    sample_agg_kernel<<<BQ, 256, 0, stream>>>(v_ws, locs_ws, attn_ws, agg_ws);

    // out = agg @ w_o + b_o  (bf16 MFMA)
    gemm_bf16<true><<<dim3(2, (BQ + 127) / 128), blk, 0, stream>>>(
        agg_ws, wt_o, b_o, (float*)d_out, BQ, 256, 256);
}

// Round 3
// 165.897 us; speedup vs baseline: 2.3552x; 1.6513x over previous
//
#include <hip/hip_runtime.h>
#include <hip/hip_bf16.h>
#include <math.h>

// Problem constants (from reference)
constexpr int B_ = 8, Q_ = 900, H_ = 8;
constexpr int S_ = 13294;
constexpr int BQ = 7200;     // B*Q
constexpr int BS = 106352;   // B*S

typedef __bf16 bf16x8 __attribute__((ext_vector_type(8)));
typedef float  f32x4  __attribute__((ext_vector_type(4)));

__device__ __forceinline__ void load_lds16(const void* g, void* lds) {
    __builtin_amdgcn_global_load_lds(
        (const __attribute__((address_space(1))) void*)g,
        (__attribute__((address_space(3))) void*)lds, 16, 0, 0);
}

// ---------------------------------------------------------------------------
// Fused transpose+cast of ALL weights into bf16 [N][K] layouts.
// wid 0..4: w_q, w_v, w_o, w_off1 (first 256 rows), w_off2  (256x256)
// wid 5   : [w_ax | w_ay] -> taxy[256][256]
// 64 tiles of 32x32 per weight -> 384 blocks.
// ---------------------------------------------------------------------------
__global__ __launch_bounds__(256)
void transpose_all(const float* __restrict__ wq, const float* __restrict__ wv,
                   const float* __restrict__ wo, const float* __restrict__ woff1,
                   const float* __restrict__ woff2, const float* __restrict__ wax,
                   const float* __restrict__ way,
                   __bf16* __restrict__ tq, __bf16* __restrict__ tv,
                   __bf16* __restrict__ to_, __bf16* __restrict__ toff1,
                   __bf16* __restrict__ toff2, __bf16* __restrict__ taxy)
{
    const int bi = blockIdx.x;
    const int wid = bi >> 6, t = bi & 63;
    const int k0 = (t & 7) * 32, n0 = (t >> 3) * 32;
    __shared__ float tile[32][33];
    const int tx = threadIdx.x & 31, ty = threadIdx.x >> 5;

    const float* src; __bf16* dst; int scol = n0; int sN = 256;
    if      (wid == 0) { src = wq;    dst = tq;    }
    else if (wid == 1) { src = wv;    dst = tv;    }
    else if (wid == 2) { src = wo;    dst = to_;   }
    else if (wid == 3) { src = woff1; dst = toff1; }
    else if (wid == 4) { src = woff2; dst = toff2; }
    else { dst = taxy; sN = 128;
           if (n0 < 128) src = wax; else { src = way; scol = n0 - 128; } }

    #pragma unroll
    for (int i = 0; i < 4; ++i)
        tile[ty + 8 * i][tx] = src[(size_t)(k0 + ty + 8 * i) * sN + scol + tx];
    __syncthreads();
    #pragma unroll
    for (int i = 0; i < 4; ++i)
        dst[(size_t)(n0 + ty + 8 * i) * 256 + k0 + tx] = (__bf16)tile[tx][ty + 8 * i];
}

// ---------------------------------------------------------------------------
// bf16 MFMA GEMM, double-buffered 2-phase pipeline.
// C[M,N] = A[M,K](f32) @ Wt[N,K](bf16) + bias (+extra2) (relu?) -> f32 or bf16
// BM=BN=128, BK=32, 4 waves (2x2), 64x64/wave, mfma_f32_16x16x32_bf16.
// A: reg-staged (prefetch f32 loads early, cvt+swizzled ds_write after MFMA)
// B: global_load_lds w/ source-side XOR swizzle (linear LDS dest).
// ---------------------------------------------------------------------------
template<bool RELU, bool EXTRA2, bool OUTBF16>
__global__ __launch_bounds__(256)
void gemm_bf16(const float* __restrict__ A, const __bf16* __restrict__ Wt,
               const float* __restrict__ bias, const float* __restrict__ extra,
               const float* __restrict__ Wex, void* __restrict__ outp,
               int M, int K, int N)
{
    __shared__ __bf16 Asb[2][128 * 32];
    __shared__ __bf16 Bsb[2][128 * 32];
    char* const Asb_b = (char*)Asb;
    char* const Bsb_b = (char*)Bsb;

    const int tid  = threadIdx.x;
    const int wave = tid >> 6, lane = tid & 63;
    const int wr = wave >> 1, wc = wave & 1;
    const int row0 = blockIdx.y * 128, col0 = blockIdx.x * 128;

    // A staging: thread t -> row=t>>1, k-half=t&1 (16 f32 each)
    const int st_row = tid >> 1, st_kh = tid & 1;
    const int gr_cl  = min(row0 + st_row, M - 1);
    const float* Abase = A + (size_t)gr_cl * K + st_kh * 16;
    const int asw   = (st_row >> 1) & 3;
    const int a_wo0 = st_row * 64 + ((st_kh * 2)     ^ asw) * 16;
    const int a_wo1 = st_row * 64 + ((st_kh * 2 + 1) ^ asw) * 16;

    // fragment read offsets (bytes within one buffer)
    int a_off[4], b_off[4];
    #pragma unroll
    for (int mi = 0; mi < 4; ++mi) {
        const int r   = wr * 64 + mi * 16 + (lane & 15);
        const int kcp = (lane >> 4) ^ ((r >> 1) & 3);
        a_off[mi] = r * 64 + kcp * 16;
    }
    #pragma unroll
    for (int ni = 0; ni < 4; ++ni) {
        const int c   = wc * 64 + ni * 16 + (lane & 15);
        const int kcp = (lane >> 4) ^ ((c >> 1) & 3);
        b_off[ni] = c * 64 + kcp * 16;
    }

    // B staging mapping
    int bst_col[2], bst_kc[2];
    #pragma unroll
    for (int i = 0; i < 2; ++i) {
        const int c   = (wave * 2 + i) * 64 + lane;
        const int col = c >> 2, kcp = c & 3;
        bst_col[i] = col;
        bst_kc[i]  = kcp ^ ((col >> 1) & 3);
    }

    auto issueB = [&](int kt, int buf) {
        #pragma unroll
        for (int i = 0; i < 2; ++i) {
            const __bf16* g = Wt + (size_t)(col0 + bst_col[i]) * K + kt * 32 + bst_kc[i] * 8;
            load_lds16(g, Bsb_b + buf * 8192 + (wave * 2 + i) * 1024);
        }
    };
    auto writeA = [&](int buf, float4 f0, float4 f1, float4 f2, float4 f3) {
        bf16x8 c0, c1;
        c0[0] = (__bf16)f0.x; c0[1] = (__bf16)f0.y; c0[2] = (__bf16)f0.z; c0[3] = (__bf16)f0.w;
        c0[4] = (__bf16)f1.x; c0[5] = (__bf16)f1.y; c0[6] = (__bf16)f1.z; c0[7] = (__bf16)f1.w;
        c1[0] = (__bf16)f2.x; c1[1] = (__bf16)f2.y; c1[2] = (__bf16)f2.z; c1[3] = (__bf16)f2.w;
        c1[4] = (__bf16)f3.x; c1[5] = (__bf16)f3.y; c1[6] = (__bf16)f3.z; c1[7] = (__bf16)f3.w;
        *(bf16x8*)(Asb_b + buf * 8192 + a_wo0) = c0;
        *(bf16x8*)(Asb_b + buf * 8192 + a_wo1) = c1;
    };

    f32x4 acc[4][4] = {};
    const int nk = K >> 5;

    // prologue: stage tile 0
    {
        issueB(0, 0);
        const float4 f0 = ((const float4*)Abase)[0];
        const float4 f1 = ((const float4*)Abase)[1];
        const float4 f2 = ((const float4*)Abase)[2];
        const float4 f3 = ((const float4*)Abase)[3];
        writeA(0, f0, f1, f2, f3);
    }
    __syncthreads();

    int buf = 0;
    for (int kt = 0; kt < nk - 1; ++kt) {
        // prefetch tile kt+1 (loads fly while we compute tile kt)
        const float* ga = Abase + (kt + 1) * 32;
        const float4 g0 = ((const float4*)ga)[0];
        const float4 g1 = ((const float4*)ga)[1];
        const float4 g2 = ((const float4*)ga)[2];
        const float4 g3 = ((const float4*)ga)[3];
        issueB(kt + 1, buf ^ 1);

        bf16x8 a[4], b[4];
        #pragma unroll
        for (int mi = 0; mi < 4; ++mi) a[mi] = *(const bf16x8*)(Asb_b + buf * 8192 + a_off[mi]);
        #pragma unroll
        for (int ni = 0; ni < 4; ++ni) b[ni] = *(const bf16x8*)(Bsb_b + buf * 8192 + b_off[ni]);
        #pragma unroll
        for (int mi = 0; mi < 4; ++mi)
            #pragma unroll
            for (int ni = 0; ni < 4; ++ni)
                acc[mi][ni] = __builtin_amdgcn_mfma_f32_16x16x32_bf16(
                    a[mi], b[ni], acc[mi][ni], 0, 0, 0);

        writeA(buf ^ 1, g0, g1, g2, g3);   // compiler waits on g-regs here
        __syncthreads();                    // tile kt+1 fully staged
        buf ^= 1;
    }

    // final tile compute
    {
        bf16x8 a[4], b[4];
        #pragma unroll
        for (int mi = 0; mi < 4; ++mi) a[mi] = *(const bf16x8*)(Asb_b + buf * 8192 + a_off[mi]);
        #pragma unroll
        for (int ni = 0; ni < 4; ++ni) b[ni] = *(const bf16x8*)(Bsb_b + buf * 8192 + b_off[ni]);
        #pragma unroll
        for (int mi = 0; mi < 4; ++mi)
            #pragma unroll
            for (int ni = 0; ni < 4; ++ni)
                acc[mi][ni] = __builtin_amdgcn_mfma_f32_16x16x32_bf16(
                    a[mi], b[ni], acc[mi][ni], 0, 0, 0);
    }

    // epilogue
    int   colb[4];
    float bb[4], we0[4], we1[4];
    #pragma unroll
    for (int ni = 0; ni < 4; ++ni) {
        colb[ni] = col0 + wc * 64 + ni * 16 + (lane & 15);
        bb[ni]   = bias[colb[ni]];
        if (EXTRA2) { we0[ni] = Wex[colb[ni]]; we1[ni] = Wex[N + colb[ni]]; }
    }
    #pragma unroll
    for (int mi = 0; mi < 4; ++mi) {
        #pragma unroll
        for (int rr = 0; rr < 4; ++rr) {
            const int row = row0 + wr * 64 + mi * 16 + (lane >> 4) * 4 + rr;
            if (row >= M) continue;
            float e0 = 0.f, e1 = 0.f;
            if (EXTRA2) { e0 = extra[(size_t)row * 2]; e1 = extra[(size_t)row * 2 + 1]; }
            #pragma unroll
            for (int ni = 0; ni < 4; ++ni) {
                float v = acc[mi][ni][rr] + bb[ni];
                if (EXTRA2) v += e0 * we0[ni] + e1 * we1[ni];
                if (RELU)   v = fmaxf(v, 0.f);
                if (OUTBF16) ((__bf16*)outp)[(size_t)row * N + colb[ni]] = (__bf16)v;
                else         ((float*)outp)[(size_t)row * N + colb[ni]] = v;
            }
        }
    }
}

// ---------------------------------------------------------------------------
// Fused: spec + softmax + locations + bilinear sampling + aggregation.
// One block per (b,q), 256 threads (h=tid>>5, d=tid&31 for sampling phase).
// ---------------------------------------------------------------------------
__device__ __forceinline__
float corner_val_bf(const __bf16* __restrict__ vb, int st, int Hl, int Wl,
                    int xi, int yi, float w, int hd)
{
    const bool valid = (xi >= 0) & (xi < Wl) & (yi >= 0) & (yi < Hl);
    const int idx = min(max(yi, 0), Hl - 1) * Wl + min(max(xi, 0), Wl - 1);
    const float g = (float)vb[(size_t)(st + idx) * 256 + hd];
    return valid ? g * w : 0.f;
}

__global__ __launch_bounds__(256)
void attn_sample_kernel(const float* __restrict__ q, const float* __restrict__ axy,
                        const float* __restrict__ bx, const float* __restrict__ by,
                        const float* __restrict__ refp, const float* __restrict__ objs,
                        const float* __restrict__ off, const __bf16* __restrict__ v,
                        float* __restrict__ agg)
{
    const int bq = blockIdx.x;
    const int b  = bq / Q_;
    const int tid = threadIdx.x;

    __shared__ float sspec[8];
    __shared__ float sm[128];
    __shared__ float sa[128];
    __shared__ float sl[256];

    // spec[h] = (q_h . bx_h) * (q_h . by_h), 32-lane group reduce
    {
        const float qa = q[(size_t)bq * 256 + tid];
        float px = qa * bx[tid], py = qa * by[tid];
        #pragma unroll
        for (int m = 16; m; m >>= 1) {
            px += __shfl_xor(px, m, 32);
            py += __shfl_xor(py, m, 32);
        }
        if ((tid & 31) == 0) sspec[tid >> 5] = px * py;
    }
    __syncthreads();

    if (tid < 128) {
        const int h = tid >> 4;
        sm[tid] = axy[(size_t)bq * 256 + tid] * axy[(size_t)bq * 256 + 128 + tid] + sspec[h];
    }
    __syncthreads();

    if (tid < 128) {
        const int h = tid >> 4;
        float mx = -1e30f;
        #pragma unroll
        for (int i = 0; i < 16; ++i) mx = fmaxf(mx, sm[h * 16 + i]);
        float s = 0.f;
        #pragma unroll
        for (int i = 0; i < 16; ++i) s += __expf(sm[h * 16 + i] - mx);
        sa[tid] = __expf(sm[tid] - mx) / s;

        const int l = (tid >> 2) & 3;
        const float os0 = objs[(size_t)bq * 2], os1 = objs[(size_t)bq * 2 + 1];
        const float r0 = refp[((size_t)bq * 4 + l) * 2];
        const float r1 = refp[((size_t)bq * 4 + l) * 2 + 1];
        const float o0 = off[(size_t)bq * 256 + tid * 2]     * os0;
        const float o1 = off[(size_t)bq * 256 + tid * 2 + 1] * os1;
        sl[tid * 2]     = fminf(fmaxf(r0 + o0, 0.f), 1.f);
        sl[tid * 2 + 1] = fminf(fmaxf(r1 + o1, 0.f), 1.f);
    }
    __syncthreads();

    const int h = tid >> 5, d = tid & 31;
    const int hd = h * 32 + d;
    const __bf16* vb = v + (size_t)b * S_ * 256;

    const int Hl_arr[4] = {100, 50, 25, 13};
    const int Wl_arr[4] = {100, 50, 25, 13};
    const int st_arr[4] = {0, 10000, 12500, 13125};

    float acc = 0.f;
    #pragma unroll
    for (int lvl = 0; lvl < 4; ++lvl) {
        const int Hl = Hl_arr[lvl], Wl = Wl_arr[lvl], st = st_arr[lvl];
        #pragma unroll
        for (int p = 0; p < 4; ++p) {
            const int li = (h * 4 + lvl) * 4 + p;
            const float lx = sl[li * 2], ly = sl[li * 2 + 1];
            const float a  = sa[li];
            const float x = lx * (float)Wl - 0.5f;
            const float y = ly * (float)Hl - 0.5f;
            const float x0f = floorf(x), y0f = floorf(y);
            const float fx = x - x0f, fy = y - y0f;
            const int x0 = (int)x0f, y0 = (int)y0f;
            const float w00 = (1.f - fx) * (1.f - fy);
            const float w10 = fx * (1.f - fy);
            const float w01 = (1.f - fx) * fy;
            const float w11 = fx * fy;
            float s = 0.f;
            s += corner_val_bf(vb, st, Hl, Wl, x0,     y0,     w00, hd);
            s += corner_val_bf(vb, st, Hl, Wl, x0 + 1, y0,     w10, hd);
            s += corner_val_bf(vb, st, Hl, Wl, x0,     y0 + 1, w01, hd);
            s += corner_val_bf(vb, st, Hl, Wl, x0 + 1, y0 + 1, w11, hd);
            acc += a * s;
        }
    }
    agg[(size_t)bq * 256 + tid] = acc;
}

// ---------------------------------------------------------------------------
extern "C" void kernel_launch(void* const* d_in, const int* in_sizes, int n_in,
                              void* d_out, int out_size, void* d_ws, size_t ws_size,
                              hipStream_t stream)
{
    const float* query = (const float*)d_in[0];
    const float* refp  = (const float*)d_in[1];
    const float* x_in  = (const float*)d_in[2];
    const float* objs  = (const float*)d_in[3];
    const float* w_q    = (const float*)d_in[6];
    const float* b_q    = (const float*)d_in[7];
    const float* w_v    = (const float*)d_in[8];
    const float* b_v    = (const float*)d_in[9];
    const float* w_o    = (const float*)d_in[10];
    const float* b_o    = (const float*)d_in[11];
    const float* w_off1 = (const float*)d_in[12];
    const float* b_off1 = (const float*)d_in[13];
    const float* w_off2 = (const float*)d_in[14];
    const float* b_off2 = (const float*)d_in[15];
    const float* w_ax   = (const float*)d_in[16];
    const float* b_ax   = (const float*)d_in[17];
    const float* w_ay   = (const float*)d_in[18];
    const float* b_ay   = (const float*)d_in[19];
    const float* bx     = (const float*)d_in[20];
    const float* by     = (const float*)d_in[21];

    float* ws = (float*)d_ws;
    float* q_ws   = ws;                             // BQ*256 f32
    float* hid_ws = q_ws   + (size_t)BQ * 256;      // BQ*256 f32
    float* off_ws = hid_ws + (size_t)BQ * 256;      // BQ*256 f32
    float* axy_ws = off_ws + (size_t)BQ * 256;      // BQ*256 f32 [ax|ay]
    float* agg_ws = axy_ws + (size_t)BQ * 256;      // BQ*256 f32
    float* baxy_ws= agg_ws + (size_t)BQ * 256;      // 256 f32 combined bias
    __bf16* v_bf  = (__bf16*)(baxy_ws + 256);       // BS*256 bf16
    __bf16* wt_q   = v_bf   + (size_t)BS * 256;
    __bf16* wt_v   = wt_q   + 256 * 256;
    __bf16* wt_o   = wt_v   + 256 * 256;
    __bf16* wt_off1= wt_o   + 256 * 256;
    __bf16* wt_off2= wt_off1+ 256 * 256;
    __bf16* wt_axy = wt_off2+ 256 * 256;

    const dim3 blk(256);

    // combined bias for [ax|ay] (tiny memcpys, async d2d)
    hipMemcpyAsync(baxy_ws,       b_ax, 128 * sizeof(float), hipMemcpyDeviceToDevice, stream);
    hipMemcpyAsync(baxy_ws + 128, b_ay, 128 * sizeof(float), hipMemcpyDeviceToDevice, stream);

    // all weight transposes in one launch
    transpose_all<<<384, blk, 0, stream>>>(w_q, w_v, w_o, w_off1, w_off2, w_ax, w_ay,
                                           wt_q, wt_v, wt_o, wt_off1, wt_off2, wt_axy);

    // v = x_in @ w_v + b_v  -> bf16
    gemm_bf16<false, false, true><<<dim3(2, (BS + 127) / 128), blk, 0, stream>>>(
        x_in, wt_v, b_v, nullptr, nullptr, v_bf, BS, 256, 256);

    // q = query @ w_q + b_q -> f32
    gemm_bf16<false, false, false><<<dim3(2, (BQ + 127) / 128), blk, 0, stream>>>(
        query, wt_q, b_q, nullptr, nullptr, q_ws, BQ, 256, 256);

    // hid = relu([q, obj] @ w_off1 + b_off1) -> f32
    gemm_bf16<true, true, false><<<dim3(2, (BQ + 127) / 128), blk, 0, stream>>>(
        q_ws, wt_off1, b_off1, objs, w_off1 + 256 * 256, hid_ws, BQ, 256, 256);

    // offsets = hid @ w_off2 + b_off2 -> f32
    gemm_bf16<false, false, false><<<dim3(2, (BQ + 127) / 128), blk, 0, stream>>>(
        hid_ws, wt_off2, b_off2, nullptr, nullptr, off_ws, BQ, 256, 256);

    // [ax | ay] = q @ [w_ax|w_ay] + [b_ax|b_ay] -> f32
    gemm_bf16<false, false, false><<<dim3(2, (BQ + 127) / 128), blk, 0, stream>>>(
        q_ws, wt_axy, baxy_ws, nullptr, nullptr, axy_ws, BQ, 256, 256);

    // fused spec/softmax/locs/sampling
    attn_sample_kernel<<<BQ, blk, 0, stream>>>(q_ws, axy_ws, bx, by, refp, objs,
                                               off_ws, v_bf, agg_ws);

    // out = agg @ w_o + b_o -> f32
    gemm_bf16<false, false, false><<<dim3(2, (BQ + 127) / 128), blk, 0, stream>>>(
        agg_ws, wt_o, b_o, nullptr, nullptr, (float*)d_out, BQ, 256, 256);
}